// Round 2
// baseline (352.061 us; speedup 1.0000x reference)
//
#include <hip/hip_runtime.h>

#define N_RAYS    131072
#define N_SAMPLES 128
#define FAR_DELTA 1e10f

// DPP controls (gfx9): row ops act within 16-lane rows (== one ray segment).
//   row_shr:n  -> lane i reads lane i-n   (shfl_up analog; prefix-scan direction)
//   row_shl:n  -> lane i reads lane i+n   (shfl_down analog)
// Lanes whose source crosses the row edge are invalid -> receive `ident`.
#define ROW_SHL(n) (0x100 + (n))
#define ROW_SHR(n) (0x110 + (n))
#define QPERM(a,b,c,d) ((a) | ((b) << 2) | ((c) << 4) | ((d) << 6))

template <int CTRL>
__device__ __forceinline__ float dpp_f(float v, float ident) {
    return __int_as_float(__builtin_amdgcn_update_dpp(
        __float_as_int(ident), __float_as_int(v), CTRL, 0xF, 0xF, false));
}

// 16 lanes per ray, 8 consecutive samples per lane, 4 rays per wave.
// Cumprod = per-lane serial product + 4-level DPP row-scan (segmented for free).
// Reduction = DPP shift-reduce (shl 8, shl 4) + quad_perm 4x4 transpose; lanes
// 0..3 of each row end with fx,fy,fz,dd and write the outputs directly.
__global__ __launch_bounds__(256) void VolumeRenderer_57612691308835_kernel(
    const float* __restrict__ density,      // [N, S]
    const float* __restrict__ feature,      // [N, S, 3]
    const float* __restrict__ depth,        // [N, S]
    float* __restrict__ out_feat,           // [N, 3]
    float* __restrict__ out_depth)          // [N]
{
    const int tid  = threadIdx.x;
    const int wave = tid >> 6;
    const int lane = tid & 63;
    const int p    = lane & 15;             // position within 16-lane row
    const int g    = lane >> 4;             // which ray of this wave
    const int ray  = (blockIdx.x << 4) + (wave << 2) + g;

    const long base = (long)ray * N_SAMPLES + p * 8;

    // Coalesced vector loads: 32B density + 32B depth + 96B feature per lane.
    const float4 dn0 = *(const float4*)(density + base);
    const float4 dn1 = *(const float4*)(density + base + 4);
    const float4 dp0 = *(const float4*)(depth + base);
    const float4 dp1 = *(const float4*)(depth + base + 4);
    const float4* fp = (const float4*)(feature + base * 3);   // 96B, 16B-aligned
    const float4 f0 = fp[0], f1 = fp[1], f2 = fp[2];
    const float4 f3 = fp[3], f4 = fp[4], f5 = fp[5];

    // deltas: depth[s+1]-depth[s]; this lane needs the NEXT lane's first depth.
    const float dnext = dpp_f<ROW_SHL(1)>(dp0.x, 0.0f);       // lane p <- lane p+1
    const float d7 = (p == 15) ? FAR_DELTA : (dnext - dp1.w);

    const float a0 = __expf(-dn0.x * (dp0.y - dp0.x));
    const float a1 = __expf(-dn0.y * (dp0.z - dp0.y));
    const float a2 = __expf(-dn0.z * (dp0.w - dp0.z));
    const float a3 = __expf(-dn0.w * (dp1.x - dp0.w));
    const float a4 = __expf(-dn1.x * (dp1.y - dp1.x));
    const float a5 = __expf(-dn1.y * (dp1.z - dp1.y));
    const float a6 = __expf(-dn1.z * (dp1.w - dp1.z));
    const float a7 = __expf(-dn1.w * d7);

    // Per-lane product (tree order), then segmented inclusive prefix scan
    // across the 16-lane row (Hillis-Steele with row_shr = read lane i-off).
    float s = ((a0 * a1) * (a2 * a3)) * ((a4 * a5) * (a6 * a7));
    s *= dpp_f<ROW_SHR(1)>(s, 1.0f);
    s *= dpp_f<ROW_SHR(2)>(s, 1.0f);
    s *= dpp_f<ROW_SHR(4)>(s, 1.0f);
    s *= dpp_f<ROW_SHR(8)>(s, 1.0f);
    float T = dpp_f<ROW_SHR(1)>(s, 1.0f);   // exclusive prefix; lane 0 -> 1.0

    // weights: w_i = T_incl_i * (1 - a_i)
    T *= a0; const float w0 = T * (1.0f - a0);
    T *= a1; const float w1 = T * (1.0f - a1);
    T *= a2; const float w2 = T * (1.0f - a2);
    T *= a3; const float w3 = T * (1.0f - a3);
    T *= a4; const float w4 = T * (1.0f - a4);
    T *= a5; const float w5 = T * (1.0f - a5);
    T *= a6; const float w6 = T * (1.0f - a6);
    T *= a7; const float w7 = T * (1.0f - a7);

    // feature element k of sample i lives at flat index 3i+k within f0..f5
    float fx = w0*f0.x + w1*f0.w + w2*f1.z + w3*f2.y + w4*f3.x + w5*f3.w + w6*f4.z + w7*f5.y;
    float fy = w0*f0.y + w1*f1.x + w2*f1.w + w3*f2.z + w4*f3.y + w5*f4.x + w6*f4.w + w7*f5.z;
    float fz = w0*f0.z + w1*f1.y + w2*f2.x + w3*f2.w + w4*f3.z + w5*f4.y + w6*f5.x + w7*f5.w;
    float dd = w0*dp0.x + w1*dp0.y + w2*dp0.z + w3*dp0.w + w4*dp1.x + w5*dp1.y + w6*dp1.z + w7*dp1.w;

    // Shift-reduce toward the LOW lanes: after shl 8 then shl 4,
    // lanes 0..3 hold the mod-4 class sums of the whole row.
    fx += dpp_f<ROW_SHL(8)>(fx, 0.0f);
    fy += dpp_f<ROW_SHL(8)>(fy, 0.0f);
    fz += dpp_f<ROW_SHL(8)>(fz, 0.0f);
    dd += dpp_f<ROW_SHL(8)>(dd, 0.0f);
    fx += dpp_f<ROW_SHL(4)>(fx, 0.0f);
    fy += dpp_f<ROW_SHL(4)>(fy, 0.0f);
    fz += dpp_f<ROW_SHL(4)>(fz, 0.0f);
    dd += dpp_f<ROW_SHL(4)>(dd, 0.0f);

    // 4x4 transpose-reduce within the quad (lanes 0..3): 3 quad_perm ops.
    // End state: lane 0 -> total fx, 1 -> fy, 2 -> fz, 3 -> dd.
    const bool o1 = (p & 1);
    const float sA = o1 ? fx : fy;
    const float rA = dpp_f<QPERM(1, 0, 3, 2)>(sA, 0.0f);   // xor 1
    if (o1) fy += rA; else fx += rA;
    const float sB = o1 ? fz : dd;
    const float rB = dpp_f<QPERM(1, 0, 3, 2)>(sB, 0.0f);   // xor 1
    if (o1) dd += rB; else fz += rB;
    const float own = (p & 2) ? (o1 ? dd : fz) : (o1 ? fy : fx);
    const float sC  = (p & 2) ? (o1 ? fy : fx) : (o1 ? dd : fz);
    const float rC  = dpp_f<QPERM(2, 3, 0, 1)>(sC, 0.0f);  // xor 2
    const float res = own + rC;

    // lane p=0,1,2 -> feat x,y,z ; p=3 -> depth
    if (p < 3)       out_feat[(long)ray * 3 + p] = res;
    else if (p == 3) out_depth[ray] = res;
}

extern "C" void kernel_launch(void* const* d_in, const int* in_sizes, int n_in,
                              void* d_out, int out_size, void* d_ws, size_t ws_size,
                              hipStream_t stream) {
    const float* density = (const float*)d_in[0];   // [N, S]
    const float* feature = (const float*)d_in[1];   // [N, S, 3]
    const float* depth   = (const float*)d_in[2];   // [N, S]

    float* out_feat  = (float*)d_out;                       // [N, 3] flat first
    float* out_depth = (float*)d_out + (long)N_RAYS * 3;    // [N] after

    const int rays_per_block = 16;                   // 4 waves x 4 rays/wave
    const int grid = N_RAYS / rays_per_block;        // 8192
    VolumeRenderer_57612691308835_kernel<<<grid, 256, 0, stream>>>(
        density, feature, depth, out_feat, out_depth);
}